// Round 12
// baseline (51.542 us; speedup 1.0000x reference)
//
#include <hip/hip_runtime.h>

// Depthwise temporal FIR (FW=64, SAME pad low=31/high=32), weight-norm +
// positivity clamp + bias. out[t,c] = b[c] + sum_f relu(w[f,c]/||w||) x[t-31+f,c]
//
// Round-12 structure: tap-split across WAVES (wave g = taps 16g..16g+15 of the
// same 64 channels), partials into 4 LDS slabs, reduce pass sums slabs + bias.
// Rationale (rounds 6-11): any per-lane live set > ~100 regs gets parked in
// AGPRs (instruction bloat ~2x, unified-file occupancy cap ~12 waves/CU);
// shuffle-based splits add cross-lane overhead. Here: live set ~76 VGPR,
// no shuffles, all LDS offsets compile-time immediates, c-blocks fastest.

#define T_DIM 4096
#define C_DIM 4096
#define PAD_L 31
#define CB    64            // channels per block
#define KTILE 256           // time steps per block
#define SUB   32            // time steps per subtile (slab depth)
#define NSUB  (KTILE / SUB)
#define TPG   16            // taps per group (wave)

template <bool GUARD>
__device__ __forceinline__ void fir_body(const float* __restrict__ x,
                                         const float* __restrict__ w,
                                         const float* __restrict__ bia,
                                         float* __restrict__ out,
                                         float* __restrict__ slab,   // [4][SUB][CB]
                                         int c, int cl, int g, int t0) {
    const float* __restrict__ xp = x + c;                 // channel column base

    // ---- weights of this wave's tap group + cross-wave weight-norm via LDS ----
    float wf[TPG];
    float ss = 0.0f;
#pragma unroll
    for (int j = 0; j < TPG; ++j) {
        wf[j] = w[(g * TPG + j) * C_DIM + c];
        ss = fmaf(wf[j], wf[j], ss);
    }
    slab[g * CB + cl] = ss;
    __syncthreads();
    ss = slab[0 * CB + cl] + slab[1 * CB + cl] + slab[2 * CB + cl] + slab[3 * CB + cl];
    __syncthreads();                                      // slab reused for y below
    const float inv = 1.0f / fmaxf(sqrtf(ss), 1e-8f);
#pragma unroll
    for (int j = 0; j < TPG; ++j) wf[j] = fmaxf(wf[j] * inv, 0.0f);

    const float bv = bia[c];

    // group g's window base: y_g[t0+K] = sum_j wf[j] x[bas + K + j]
    const int bas = t0 - PAD_L + TPG * g;                 // bas % 16 == 1

    // guarded column load (wave-uniform condition; folds away when !GUARD)
#define LOADX(m) ((!GUARD || ((unsigned)(m) < (unsigned)T_DIM))                \
                      ? xp[(long long)(m) * C_DIM] : 0.0f)

    // ---- circular window: slot(m) = m & 15; warm-up x[bas .. bas+15] ----
    float xbuf[TPG];
#pragma unroll
    for (int i = 0; i < TPG; ++i) xbuf[(1 + i) & 15] = LOADX(bas + i);

    // prefetch: pfA feeds inserts of steps 0..15, pfB steps 16..31
    float pfA[16], pfB[16];
#pragma unroll
    for (int i = 0; i < 16; ++i) pfA[i] = LOADX(bas + 16 + i);

    float* __restrict__ yslab = slab + g * (SUB * CB) + cl;       // write base
    const float* __restrict__ rbase = slab + g * (8 * CB) + cl;   // reduce base

    // one FIR step; k is a compile-time constant 0..31 (k%16 static slots)
#define FIR_STEP(k, src)                                                      \
    {                                                                         \
        float a0 = 0.0f, a1 = 0.0f;                                           \
        _Pragma("unroll")                                                     \
        for (int j = 0; j < TPG; j += 2) {                                    \
            a0 = fmaf(wf[j],     xbuf[(1 + (k) + j) & 15],     a0);           \
            a1 = fmaf(wf[j + 1], xbuf[(1 + (k) + j + 1) & 15], a1);           \
        }                                                                     \
        yslab[(k) * CB] = a0 + a1;          /* ds_write, imm offset */        \
        xbuf[(1 + (k)) & 15] = src[(k) & 15];                                 \
    }

#pragma unroll 1
    for (int S = 0; S < NSUB; ++S) {
        const int kb = S * SUB;
        // pfB for this subtile (inserts of steps 16..31): m = bas+kb+32+i
#pragma unroll
        for (int i = 0; i < 16; ++i) pfB[i] = LOADX(bas + kb + 32 + i);

        FIR_STEP(0,  pfA) FIR_STEP(1,  pfA) FIR_STEP(2,  pfA) FIR_STEP(3,  pfA)
        FIR_STEP(4,  pfA) FIR_STEP(5,  pfA) FIR_STEP(6,  pfA) FIR_STEP(7,  pfA)
        FIR_STEP(8,  pfA) FIR_STEP(9,  pfA) FIR_STEP(10, pfA) FIR_STEP(11, pfA)
        FIR_STEP(12, pfA) FIR_STEP(13, pfA) FIR_STEP(14, pfA) FIR_STEP(15, pfA)

        if (S < NSUB - 1) {   // pfA for next subtile: m = bas+(kb+32)+16+i
#pragma unroll
            for (int i = 0; i < 16; ++i) pfA[i] = LOADX(bas + kb + 48 + i);
        }

        FIR_STEP(16, pfB) FIR_STEP(17, pfB) FIR_STEP(18, pfB) FIR_STEP(19, pfB)
        FIR_STEP(20, pfB) FIR_STEP(21, pfB) FIR_STEP(22, pfB) FIR_STEP(23, pfB)
        FIR_STEP(24, pfB) FIR_STEP(25, pfB) FIR_STEP(26, pfB) FIR_STEP(27, pfB)
        FIR_STEP(28, pfB) FIR_STEP(29, pfB) FIR_STEP(30, pfB) FIR_STEP(31, pfB)

        __syncthreads();     // slab complete for this subtile

        // ---- reduce: wave g stores rows t_loc = g*8 .. g*8+7 (coalesced) ----
        float* __restrict__ op = out + ((long long)(t0 + kb + g * 8)) * C_DIM + c;
#pragma unroll
        for (int i = 0; i < 8; ++i) {
            const float r = rbase[0 * (SUB * CB) + i * CB]
                          + rbase[1 * (SUB * CB) + i * CB]
                          + rbase[2 * (SUB * CB) + i * CB]
                          + rbase[3 * (SUB * CB) + i * CB] + bv;
            __builtin_nontemporal_store(r, op + (long long)i * C_DIM);
        }
        __syncthreads();     // slab may be overwritten by next subtile
    }

#undef FIR_STEP
#undef LOADX
}

__global__ __launch_bounds__(256)
__attribute__((amdgpu_waves_per_eu(2, 4)))
void depthwise_fir_kernel(const float* __restrict__ x, const float* __restrict__ w,
                          const float* __restrict__ bia, float* __restrict__ out) {
    __shared__ float slab[4 * SUB * CB];                  // 32 KiB

    const int tid = threadIdx.x;
    const int g   = tid >> 6;                             // wave id = tap group
    const int cl  = tid & 63;                             // channel within block
    const int c   = blockIdx.x * CB + cl;                 // c-blocks fastest (R11)
    const int t0  = blockIdx.y * KTILE;

    if (blockIdx.y == 0 || blockIdx.y == gridDim.y - 1)
        fir_body<true>(x, w, bia, out, slab, c, cl, g, t0);
    else
        fir_body<false>(x, w, bia, out, slab, c, cl, g, t0);
}

extern "C" void kernel_launch(void* const* d_in, const int* in_sizes, int n_in,
                              void* d_out, int out_size, void* d_ws, size_t ws_size,
                              hipStream_t stream) {
    const float* x = (const float*)d_in[0];   // [T, C]
    const float* w = (const float*)d_in[1];   // [FW, C]
    const float* b = (const float*)d_in[2];   // [C]
    float* out = (float*)d_out;               // [T, C]

    dim3 grid(C_DIM / CB, T_DIM / KTILE);     // 64 x 16 = 1024 blocks = 4/CU
    dim3 block(256);
    hipLaunchKernelGGL(depthwise_fir_kernel, grid, block, 0, stream, x, w, b, out);
}